// Round 2
// baseline (299.702 us; speedup 1.0000x reference)
//
#include <hip/hip_runtime.h>
#include <math.h>

#define BATCH 32
#define CH    256
#define HH    56
#define WW    56
#define HW    3136
#define KS    7
#define KK    49
#define PSTR  52            // padded per-image stride of p (floats), 16B-multiple
#define NIMG  8192          // BATCH*CH

// conv geometry
#define IPB        4                  // images per block
#define CPITCH     64                 // padded row: 4 zeros + 56 + 4 zeros
#define CROWS      62                 // 3 + 56 + 3
#define IMG_LDS    (CROWS*CPITCH+24)  // +24 floats: per-image bank twist
#define CONV_THREADS 448              // 4 images x 112 threads

// ---------------- Kernel 1: 8x8 block-mean pool -> p[B*C, 52] ----------------
__global__ __launch_bounds__(256) void pool_kernel(const float* __restrict__ x,
                                                   float* __restrict__ p) {
    __shared__ __align__(16) float tile[HW];
    const int img = blockIdx.x;
    const int t = threadIdx.x;
    const float4* xi4 = (const float4*)(x + (size_t)img * HW);
    float4* t4 = (float4*)tile;
    #pragma unroll
    for (int i = t; i < HW / 4; i += 256) t4[i] = xi4[i];
    __syncthreads();
    if (t < 196) {                       // 49 outputs x 4 partial threads (2 rows each)
        const int o = t >> 2, part = t & 3;
        const int pr = o / KS, pc = o % KS;
        float s = 0.f;
        #pragma unroll
        for (int r = 0; r < 2; ++r) {
            const int base = (pr * 8 + part * 2 + r) * WW + pc * 8;
            #pragma unroll
            for (int c = 0; c < 8; ++c) s += tile[base + c];
        }
        s += __shfl_down(s, 2, 64);
        s += __shfl_down(s, 1, 64);
        if (part == 0) p[(size_t)img * PSTR + o] = s * (1.0f / 64.0f);
    }
}

// ------------- Kernel 2: BN batch stats per channel -> scale/shift ----------
__global__ __launch_bounds__(256) void bnstats_kernel(const float* __restrict__ p,
                                                      const float* __restrict__ gamma,
                                                      const float* __restrict__ beta,
                                                      float* __restrict__ scale,
                                                      float* __restrict__ shift) {
    const int c = blockIdx.x;
    float s = 0.f, s2 = 0.f;
    for (int tt = threadIdx.x; tt < BATCH * KK; tt += 256) {
        const int b = tt / KK, i = tt - b * KK;
        const float v = p[((size_t)(b * CH) + c) * PSTR + i];
        s += v; s2 += v * v;
    }
    #pragma unroll
    for (int o = 32; o >= 1; o >>= 1) {
        s  += __shfl_down(s, o, 64);
        s2 += __shfl_down(s2, o, 64);
    }
    __shared__ float r1[4], r2[4];
    const int w = threadIdx.x >> 6;
    if ((threadIdx.x & 63) == 0) { r1[w] = s; r2[w] = s2; }
    __syncthreads();
    if (threadIdx.x == 0) {
        const float S  = r1[0] + r1[1] + r1[2] + r1[3];
        const float S2 = r2[0] + r2[1] + r2[2] + r2[3];
        const float inv = 1.0f / (float)(BATCH * KK);
        const float mu  = S * inv;
        const float var = S2 * inv - mu * mu;       // biased, matches ref
        const float rstd = rsqrtf(var + 1e-5f);
        const float sc = gamma[c] * rstd;
        scale[c] = sc;
        shift[c] = beta[c] - mu * sc;
    }
}

// --- Kernel 3: BN-apply + Linear(49->7) + LayerNorm(C,7) + sigmoid + Linear(7->49) ---
__global__ __launch_bounds__(256) void mid_kernel(const float* __restrict__ p,
                                                  const float* __restrict__ scale,
                                                  const float* __restrict__ shift,
                                                  const float* __restrict__ w0,
                                                  const float* __restrict__ lng,
                                                  const float* __restrict__ lnb,
                                                  const float* __restrict__ w1,
                                                  float* __restrict__ ker) {
    const int b = blockIdx.x, c = threadIdx.x;
    __shared__ float s_w0[KS * KK], s_w1[KK * KS];
    __shared__ float r1[4], r2[4];
    for (int i = threadIdx.x; i < KS * KK; i += 256) { s_w0[i] = w0[i]; s_w1[i] = w1[i]; }
    __syncthreads();
    float tmp[PSTR];
    const float4* pp4 = (const float4*)(p + ((size_t)(b * CH) + c) * PSTR);
    #pragma unroll
    for (int q = 0; q < PSTR / 4; ++q) ((float4*)tmp)[q] = pp4[q];
    const float sc = scale[c], sh = shift[c];
    float pn[KK];
    #pragma unroll
    for (int i = 0; i < KK; ++i) pn[i] = tmp[i] * sc + sh;
    float v[KS];
    float ls = 0.f, ls2 = 0.f;
    #pragma unroll
    for (int j = 0; j < KS; ++j) {
        float a = 0.f;
        #pragma unroll
        for (int i = 0; i < KK; ++i) a += pn[i] * s_w0[j * KK + i];   // v = pn @ w0^T
        v[j] = a; ls += a; ls2 += a * a;
    }
    #pragma unroll
    for (int o = 32; o >= 1; o >>= 1) {
        ls  += __shfl_down(ls, o, 64);
        ls2 += __shfl_down(ls2, o, 64);
    }
    const int w = threadIdx.x >> 6;
    if ((threadIdx.x & 63) == 0) { r1[w] = ls; r2[w] = ls2; }
    __syncthreads();
    const float S  = r1[0] + r1[1] + r1[2] + r1[3];
    const float S2 = r2[0] + r2[1] + r2[2] + r2[3];
    const float inv = 1.0f / (float)(CH * KS);
    const float m   = S * inv;
    const float var = S2 * inv - m * m;             // biased, matches ref
    const float rs  = rsqrtf(var + 1e-5f);
    float sg[KS];
    #pragma unroll
    for (int j = 0; j < KS; ++j) {
        const float vn = (v[j] - m) * rs * lng[c * KS + j] + lnb[c * KS + j];
        sg[j] = 1.0f / (1.0f + expf(-vn));
    }
    float* ko = ker + ((size_t)(b * CH) + c) * KK;
    #pragma unroll
    for (int i = 0; i < KK; ++i) {
        float a = 0.f;
        #pragma unroll
        for (int j = 0; j < KS; ++j) a += sg[j] * s_w1[i * KS + j];   // @ w1^T
        ko[i] = a;
    }
}

// ------- Kernel 4: depthwise 7x7 'SAME' conv, 4-col x 7-row tiles, b128 LDS --------
// block = 4 images; thread (li, g, s): cols 4g..4g+3, rows 7s..7s+6 of image li.
// LDS layout: pad[li][row 0..61][64 cols: 4 zero | 56 | 4 zero], per-image stride
// +24 floats so all waves' ds_read_b128 spread over all 8 bank-slots.
__global__ __launch_bounds__(CONV_THREADS, 4) void conv_kernel(const float* __restrict__ x,
                                                               const float* __restrict__ ker,
                                                               float* __restrict__ out) {
    __shared__ __align__(16) float pad[IPB * IMG_LDS];   // 63872 B
    __shared__ __align__(16) float kf[IPB * KK];         // 784 B
    const int t = threadIdx.x;
    const int img0 = blockIdx.x * IPB;

    // zero whole padded region (borders + gaps)
    float4* p4 = (float4*)pad;
    const float4 z = make_float4(0.f, 0.f, 0.f, 0.f);
    #pragma unroll
    for (int i = t; i < (IPB * IMG_LDS) / 4; i += CONV_THREADS) p4[i] = z;
    if (t < IPB * KK) kf[t] = ker[(size_t)img0 * KK + t];
    __syncthreads();

    // stage interiors: 4 img x 56 rows x 14 float4 = 3136 tasks, 7 per thread
    #pragma unroll
    for (int k = 0; k < 7; ++k) {
        const int task = k * CONV_THREADS + t;
        const int li  = task / 784;           // 784 = 56*14
        const int rem = task - li * 784;
        const int row = rem / 14;
        const int q   = rem - row * 14;
        const float4 v = *(const float4*)(x + (size_t)(img0 + li) * HW + row * WW + q * 4);
        *(float4*)(pad + li * IMG_LDS + (row + 3) * CPITCH + 4 + q * 4) = v;
    }
    __syncthreads();

    const int li = t / 112;
    const int ti = t - li * 112;
    const int g  = ti >> 3;        // col group 0..13  (li/8 mapping -> perfect bank spread)
    const int s  = ti & 7;         // row strip 0..7
    const float* P = pad + li * IMG_LDS + (7 * s) * CPITCH + 4 * g;

    float kv[KK];
    #pragma unroll
    for (int i = 0; i < KK; ++i) kv[i] = kf[li * KK + i];   // LDS broadcast

    float acc[KS][4];
    #pragma unroll
    for (int r = 0; r < KS; ++r)
        #pragma unroll
        for (int c = 0; c < 4; ++c) acc[r][c] = 0.f;

    #pragma unroll
    for (int j = 0; j < 13; ++j) {
        const float4 A = *(const float4*)(P + j * CPITCH);
        const float4 Bv = *(const float4*)(P + j * CPITCH + 4);
        const float4 Cv = *(const float4*)(P + j * CPITCH + 8);
        const float w[12] = {A.x, A.y, A.z, A.w, Bv.x, Bv.y, Bv.z, Bv.w,
                             Cv.x, Cv.y, Cv.z, Cv.w};
        #pragma unroll
        for (int kr = 0; kr < KS; ++kr) {
            const int rr = j - kr;
            if (rr < 0 || rr > 6) continue;           // compile-time after unroll
            #pragma unroll
            for (int kw = 0; kw < KS; ++kw) {
                const float kvv = kv[kr * KS + kw];
                #pragma unroll
                for (int c = 0; c < 4; ++c)
                    acc[rr][c] += w[kw + 1 + c] * kvv;   // pad shifted left by 1
            }
        }
    }

    float* O = out + (size_t)(img0 + li) * HW + (7 * s) * WW + 4 * g;
    #pragma unroll
    for (int rr = 0; rr < KS; ++rr)
        *(float4*)(O + rr * WW) = make_float4(acc[rr][0], acc[rr][1], acc[rr][2], acc[rr][3]);
}

extern "C" void kernel_launch(void* const* d_in, const int* in_sizes, int n_in,
                              void* d_out, int out_size, void* d_ws, size_t ws_size,
                              hipStream_t stream) {
    const float* x   = (const float*)d_in[0];
    const float* bng = (const float*)d_in[1];
    const float* bnb = (const float*)d_in[2];
    const float* w0  = (const float*)d_in[3];
    const float* lng = (const float*)d_in[4];
    const float* lnb = (const float*)d_in[5];
    const float* w1  = (const float*)d_in[6];
    float* out = (float*)d_out;

    float* ws    = (float*)d_ws;
    float* p     = ws;                        // NIMG*PSTR floats
    float* scale = p + (size_t)NIMG * PSTR;   // CH
    float* shift = scale + CH;                // CH
    float* kern  = shift + CH;                // NIMG*KK

    hipLaunchKernelGGL(pool_kernel,    dim3(NIMG),     dim3(256), 0, stream, x, p);
    hipLaunchKernelGGL(bnstats_kernel, dim3(CH),       dim3(256), 0, stream, p, bng, bnb, scale, shift);
    hipLaunchKernelGGL(mid_kernel,     dim3(BATCH),    dim3(256), 0, stream, p, scale, shift,
                       w0, lng, lnb, w1, kern);
    hipLaunchKernelGGL(conv_kernel,    dim3(NIMG/IPB), dim3(CONV_THREADS), 0, stream, x, kern, out);
}